// Round 7
// baseline (715.061 us; speedup 1.0000x reference)
//
#include <hip/hip_runtime.h>

// GNN TARnet: h = x*emb -> 2x graph conv -> two prob heads.
// R10: k_conv occupancy/latency fix. R9 measured k_conv: 101us, VALU 22%,
//     HBM 16%, occupancy 44% (grid-capped: 625 blocks = 5000 waves < 8192).
//     => latency-bound with idle pipes. Change: 32 rows/block (grid 1250,
//     LDS 16.5KB, up to 32 waves/CU), 4 rows/wave serial (was 8), gather
//     unroll x4 (16 concurrent row-loads per row-group; VGPR=24 has room).
//     All other kernels byte-identical to R9.

constexpr int B = 8, N = 5000, E = 160000, D = 64, H = 128;
constexpr int BN = B * N;           // 40000
constexpr int ND = N * D;           // 320000
constexpr long BND = (long)BN * D;  // 2,560,000
constexpr int KC = 320;             // k-chunk per head block
constexpr int NIT = KC / 8;         // 40 k-iters per thread
constexpr int XB = ND / KC;         // 1000 x-blocks per head

using f32x4 = __attribute__((ext_vector_type(4))) float;

__device__ __forceinline__ float elu_f(float x) {
    return x > 0.0f ? x : __expf(x) - 1.0f;
}

__device__ __forceinline__ void g2lds16(const float* g, float* l) {
    __builtin_amdgcn_global_load_lds(
        (const __attribute__((address_space(1))) void*)g,
        (__attribute__((address_space(3))) void*)l, 16, 0, 0);
}

// ---------------- CSR build (edges grouped by child) ----------------
__global__ __launch_bounds__(256) void k_count(const int* __restrict__ edges,
                                               int* __restrict__ cnt) {
    int i = blockIdx.x * 256 + threadIdx.x;
    if (i < E) atomicAdd(&cnt[edges[2 * i + 1]], 1);
}

__global__ __launch_bounds__(256) void k_scan(const int* __restrict__ cnt,
                                              int* __restrict__ offs) {
    __shared__ int part[256];
    int t = threadIdx.x;
    const int CH = 20;
    int base = t * CH;
    int s = 0;
    for (int i = 0; i < CH; ++i) { int idx = base + i; if (idx < N) s += cnt[idx]; }
    part[t] = s;
    __syncthreads();
    for (int off = 1; off < 256; off <<= 1) {
        int add = (t >= off) ? part[t - off] : 0;
        __syncthreads();
        part[t] += add;
        __syncthreads();
    }
    int run = part[t] - s;
    for (int i = 0; i < CH; ++i) {
        int idx = base + i;
        if (idx < N) { offs[idx] = run; run += cnt[idx]; }
    }
    if (t == 255) offs[N] = run;
}

__global__ __launch_bounds__(256) void k_fill(const int* __restrict__ edges,
                                              const int* __restrict__ offs,
                                              int* __restrict__ cursor,
                                              int* __restrict__ elist) {
    int i = blockIdx.x * 256 + threadIdx.x;
    if (i < E) {
        int child = edges[2 * i + 1];
        int pos = offs[child] + atomicAdd(&cursor[child], 1);
        elist[pos] = edges[2 * i];
    }
}

// ---------------- prepare (conv1 only): M = elu(elu(h @ W1) @ W2) ----------------
__global__ __launch_bounds__(512) void k_prepare(const float* __restrict__ xsrc,
                                                 const float* __restrict__ emb,
                                                 const float* __restrict__ hin,
                                                 const float* __restrict__ W1,
                                                 const float* __restrict__ W2,
                                                 float* __restrict__ M,
                                                 float* __restrict__ hwt) {
    __shared__ float sW1[64 * 64];      // 16 KB
    __shared__ float sP[128 * 65];      // 33.3 KB
    int t = threadIdx.x;
    int r0 = blockIdx.x * 128;
    for (int i = t; i < 4096; i += 512) sW1[i] = W1[i];
    if (xsrc) {
        for (int i = t; i < 128 * 64; i += 512) {
            int r = i >> 6, c = i & 63;
            int row = r0 + r;
            float v = 0.0f;
            if (row < BN) {
                int n = row % N;
                v = xsrc[row] * emb[n * 64 + c];
                hwt[(long)row * 64 + c] = v;
            }
            sP[r * 65 + c] = v;
        }
    } else {
        for (int i = t; i < 128 * 64; i += 512) {
            int r = i >> 6, c = i & 63;
            int row = r0 + r;
            sP[r * 65 + c] = (row < BN) ? hin[(long)row * 64 + c] : 0.0f;
        }
    }
    __syncthreads();

    int cg = t & 15, rg = t >> 4;
    float acc[4][4] = {};
    #pragma unroll 4
    for (int k = 0; k < 64; ++k) {
        float a[4];
        #pragma unroll
        for (int i = 0; i < 4; ++i) a[i] = sP[(rg * 4 + i) * 65 + k];
        float4 bb = *reinterpret_cast<const float4*>(&sW1[k * 64 + cg * 4]);
        #pragma unroll
        for (int i = 0; i < 4; ++i) {
            acc[i][0] += a[i] * bb.x; acc[i][1] += a[i] * bb.y;
            acc[i][2] += a[i] * bb.z; acc[i][3] += a[i] * bb.w;
        }
    }
    __syncthreads();
    #pragma unroll
    for (int i = 0; i < 4; ++i)
        #pragma unroll
        for (int j = 0; j < 4; ++j)
            sP[(rg * 4 + i) * 65 + cg * 4 + j] = elu_f(acc[i][j]);
    __syncthreads();

    float acc2[4][4] = {};
    #pragma unroll 4
    for (int k = 0; k < 64; ++k) {
        float a[4];
        #pragma unroll
        for (int i = 0; i < 4; ++i) a[i] = sP[(rg * 4 + i) * 65 + k];
        float4 bb = *reinterpret_cast<const float4*>(&W2[k * 64 + cg * 4]);
        #pragma unroll
        for (int i = 0; i < 4; ++i) {
            acc2[i][0] += a[i] * bb.x; acc2[i][1] += a[i] * bb.y;
            acc2[i][2] += a[i] * bb.z; acc2[i][3] += a[i] * bb.w;
        }
    }
    #pragma unroll
    for (int i = 0; i < 4; ++i) {
        int row = r0 + rg * 4 + i;
        if (row < BN) {
            float4 o = make_float4(elu_f(acc2[i][0]), elu_f(acc2[i][1]),
                                   elu_f(acc2[i][2]), elu_f(acc2[i][3]));
            *reinterpret_cast<float4*>(&M[(long)row * 64 + cg * 4]) = o;
        }
    }
}

// ---------------- fused conv: gather + update FFN (+ optional next-prepare) ----
// R10: 32 rows/block, grid 1250, LDS 16.5KB -> 4 blocks/CU (32 waves).
// Gather: 4 rows/wave serial, edge loop unroll x4. GEMMs: 1 row/thread.
template <int PREP>
__global__ __launch_bounds__(512, 8) void k_conv(const float* __restrict__ h,
                                                 const float* __restrict__ M,
                                                 const int* __restrict__ offs,
                                                 const int* __restrict__ elist,
                                                 const float* __restrict__ W1u,  // [128][64]
                                                 const float* __restrict__ b1u,
                                                 const float* __restrict__ W2u,  // [64][64]
                                                 const float* __restrict__ b2u,
                                                 float* __restrict__ hout,
                                                 const float* __restrict__ W1p,  // [64][64]
                                                 const float* __restrict__ W2p,  // [64][64]
                                                 float* __restrict__ Mout) {
    __shared__ float sP[32 * 129];      // 16.5 KB
    int t = threadIdx.x;
    long r0 = (long)blockIdx.x * 32;

    // A1: stage h rows -> sP cols [0,64)  (32*16 = 512 float4, one/thread)
    {
        int r = t >> 4, c4 = t & 15;
        float4 v = *reinterpret_cast<const float4*>(&h[(r0 + r) * 64 + c4 * 4]);
        int base = r * 129 + c4 * 4;
        sP[base + 0] = v.x; sP[base + 1] = v.y;
        sP[base + 2] = v.z; sP[base + 3] = v.w;
    }
    // A2: gather agg rows -> sP cols [64,128); 4 rows/wave, unroll x4
    {
        int wv = t >> 6, lane = t & 63;
        int h4 = lane & 15, le = lane >> 4;
        for (int rr = 0; rr < 4; ++rr) {
            int r = wv * 4 + rr;
            long row = r0 + r;
            int b = (int)(row / N);
            int n = (int)(row - (long)b * N);
            int e0 = offs[n], e1 = offs[n + 1];
            const float* Mb = M + (long)b * ND;
            float4 a1 = make_float4(0.f, 0.f, 0.f, 0.f);
            float4 a2 = make_float4(0.f, 0.f, 0.f, 0.f);
            float4 a3 = make_float4(0.f, 0.f, 0.f, 0.f);
            float4 a4 = make_float4(0.f, 0.f, 0.f, 0.f);
            int e = e0 + le;
            for (; e + 12 < e1; e += 16) {
                int p1 = elist[e];
                int p2 = elist[e + 4];
                int p3 = elist[e + 8];
                int p4 = elist[e + 12];
                float4 v1 = *reinterpret_cast<const float4*>(&Mb[(long)p1 * 64 + h4 * 4]);
                float4 v2 = *reinterpret_cast<const float4*>(&Mb[(long)p2 * 64 + h4 * 4]);
                float4 v3 = *reinterpret_cast<const float4*>(&Mb[(long)p3 * 64 + h4 * 4]);
                float4 v4 = *reinterpret_cast<const float4*>(&Mb[(long)p4 * 64 + h4 * 4]);
                a1.x += v1.x; a1.y += v1.y; a1.z += v1.z; a1.w += v1.w;
                a2.x += v2.x; a2.y += v2.y; a2.z += v2.z; a2.w += v2.w;
                a3.x += v3.x; a3.y += v3.y; a3.z += v3.z; a3.w += v3.w;
                a4.x += v4.x; a4.y += v4.y; a4.z += v4.z; a4.w += v4.w;
            }
            for (; e < e1; e += 4) {
                int p = elist[e];
                float4 v = *reinterpret_cast<const float4*>(&Mb[(long)p * 64 + h4 * 4]);
                a1.x += v.x; a1.y += v.y; a1.z += v.z; a1.w += v.w;
            }
            a1.x += a2.x + a3.x + a4.x;
            a1.y += a2.y + a3.y + a4.y;
            a1.z += a2.z + a3.z + a4.z;
            a1.w += a2.w + a3.w + a4.w;
            #pragma unroll
            for (int m = 16; m <= 32; m <<= 1) {
                a1.x += __shfl_xor(a1.x, m);
                a1.y += __shfl_xor(a1.y, m);
                a1.z += __shfl_xor(a1.z, m);
                a1.w += __shfl_xor(a1.w, m);
            }
            if (le == 0) {
                int base = r * 129 + 64 + h4 * 4;
                sP[base + 0] = a1.x; sP[base + 1] = a1.y;
                sP[base + 2] = a1.z; sP[base + 3] = a1.w;
            }
        }
    }
    __syncthreads();

    int cg = t & 15, rg = t >> 4;   // rg in [0,32): one row per thread
    // B: update GEMM1 over k=0..128 (W1u rows broadcast from global/L1)
    float acc[4] = {};
    #pragma unroll 4
    for (int k = 0; k < 128; ++k) {
        float a0 = sP[rg * 129 + k];
        float4 bb = *reinterpret_cast<const float4*>(&W1u[k * 64 + cg * 4]);
        acc[0] += a0 * bb.x; acc[1] += a0 * bb.y;
        acc[2] += a0 * bb.z; acc[3] += a0 * bb.w;
    }
    float4 bv1 = *reinterpret_cast<const float4*>(&b1u[cg * 4]);
    __syncthreads();
    {
        int base = rg * 129 + cg * 4;
        sP[base + 0] = elu_f(acc[0] + bv1.x);
        sP[base + 1] = elu_f(acc[1] + bv1.y);
        sP[base + 2] = elu_f(acc[2] + bv1.z);
        sP[base + 3] = elu_f(acc[3] + bv1.w);
    }
    __syncthreads();

    // C: update GEMM2 over k=0..64
    float acc2[4] = {};
    #pragma unroll 4
    for (int k = 0; k < 64; ++k) {
        float a0 = sP[rg * 129 + k];
        float4 bb = *reinterpret_cast<const float4*>(&W2u[k * 64 + cg * 4]);
        acc2[0] += a0 * bb.x; acc2[1] += a0 * bb.y;
        acc2[2] += a0 * bb.z; acc2[3] += a0 * bb.w;
    }
    float4 bv2 = *reinterpret_cast<const float4*>(&b2u[cg * 4]);
    {
        float4 o = make_float4(acc2[0] + bv2.x, acc2[1] + bv2.y,
                               acc2[2] + bv2.z, acc2[3] + bv2.w);
        *reinterpret_cast<float4*>(&hout[(r0 + rg) * 64 + cg * 4]) = o;
        if (PREP) {  // stash into sP cols [64,128) (disjoint from GEMM2 reads)
            int base = rg * 129 + 64 + cg * 4;
            sP[base + 0] = o.x; sP[base + 1] = o.y;
            sP[base + 2] = o.z; sP[base + 3] = o.w;
        }
    }

    if (PREP) {
        __syncthreads();
        // D1: p1 = elu(rows @ W1p), reads sP cols [64,128), writes cols [0,64)
        float acc3[4] = {};
        #pragma unroll 4
        for (int k = 0; k < 64; ++k) {
            float a0 = sP[rg * 129 + 64 + k];
            float4 bb = *reinterpret_cast<const float4*>(&W1p[k * 64 + cg * 4]);
            acc3[0] += a0 * bb.x; acc3[1] += a0 * bb.y;
            acc3[2] += a0 * bb.z; acc3[3] += a0 * bb.w;
        }
        {
            int base = rg * 129 + cg * 4;
            sP[base + 0] = elu_f(acc3[0]);
            sP[base + 1] = elu_f(acc3[1]);
            sP[base + 2] = elu_f(acc3[2]);
            sP[base + 3] = elu_f(acc3[3]);
        }
        __syncthreads();
        // D2: Mout = elu(p1 @ W2p)
        float acc4[4] = {};
        #pragma unroll 4
        for (int k = 0; k < 64; ++k) {
            float a0 = sP[rg * 129 + k];
            float4 bb = *reinterpret_cast<const float4*>(&W2p[k * 64 + cg * 4]);
            acc4[0] += a0 * bb.x; acc4[1] += a0 * bb.y;
            acc4[2] += a0 * bb.z; acc4[3] += a0 * bb.w;
        }
        {
            float4 o = make_float4(elu_f(acc4[0]), elu_f(acc4[1]),
                                   elu_f(acc4[2]), elu_f(acc4[3]));
            *reinterpret_cast<float4*>(&Mout[(r0 + rg) * 64 + cg * 4]) = o;
        }
    }
}

// ---------------- partial[xb,:] = per-block head GEMV partial (ONE head) ------
// One head per dispatch; hot loop identical to R6/R8.
__global__ __launch_bounds__(256) void k_head(const float* __restrict__ phi,   // [8][ND]
                                              const float* __restrict__ wa,    // [ND][H]
                                              float* __restrict__ part) {      // [XB][1024]
    __shared__ float smem[4 * 32 * 33];              // 16.9 KB; phi chunk + partials
    __shared__ __align__(16) float wb[8][1024];      // 32 KB ring (8 x 4KB)
    int t = threadIdx.x;
    int k0 = blockIdx.x * KC;

    #pragma unroll
    for (int b = 0; b < 8; ++b)
        for (int kk = t; kk < KC; kk += 256)
            smem[b * KC + kk] = phi[(long)b * ND + k0 + kk];
    __syncthreads();

    int w = t >> 6, l = t & 63;
    int h4 = l & 31, kh = l >> 5;
    int kl = w * 2 + kh;                       // [0,8)
    const float* wp = wa + (long)(k0 + kl) * H + h4 * 4;

    float4 acc[8];
    #pragma unroll
    for (int b = 0; b < 8; ++b) acc[b] = make_float4(0.f, 0.f, 0.f, 0.f);

    unsigned my_off =
        (unsigned)(size_t)(__attribute__((address_space(3))) float*)&wb[0][0]
        + (unsigned)t * 16u;

    const float* wq = wp;
    #pragma unroll
    for (int j = 0; j < 8; ++j) {
        g2lds16(wq, &wb[j][w * 256]);
        wq += 8 * H;
    }

#define STEP(I, CNT, OFF, RE)                                              \
    {                                                                      \
        asm volatile("s_waitcnt vmcnt(" #CNT ")" ::: "memory");            \
        __builtin_amdgcn_sched_barrier(0);                                 \
        f32x4 w4;                                                          \
        asm volatile("ds_read_b128 %0, %1 offset:" #OFF                    \
                     : "=v"(w4) : "v"(my_off));                            \
        float pv[8];                                                       \
        _Pragma("unroll")                                                  \
        for (int b = 0; b < 8; ++b)                                        \
            pv[b] = smem[b * KC + (I) * 8 + kl];                           \
        asm volatile("s_waitcnt lgkmcnt(0)" ::: "memory");                 \
        __builtin_amdgcn_sched_barrier(0);                                 \
        _Pragma("unroll")                                                  \
        for (int b = 0; b < 8; ++b) {                                      \
            acc[b].x += pv[b] * w4.x; acc[b].y += pv[b] * w4.y;            \
            acc[b].z += pv[b] * w4.z; acc[b].w += pv[b] * w4.w;            \
        }                                                                  \
        if (RE) {                                                          \
            g2lds16(wq, &wb[(I) & 7][w * 256]);                            \
            wq += 8 * H;                                                   \
        }                                                                  \
    }

#define ROUND8(BASE, RE)                                                   \
    STEP(BASE + 0, 7, 0,     RE) STEP(BASE + 1, 7, 4096,  RE)              \
    STEP(BASE + 2, 7, 8192,  RE) STEP(BASE + 3, 7, 12288, RE)              \
    STEP(BASE + 4, 7, 16384, RE) STEP(BASE + 5, 7, 20480, RE)              \
    STEP(BASE + 6, 7, 24576, RE) STEP(BASE + 7, 7, 28672, RE)

    ROUND8(0, 1) ROUND8(8, 1) ROUND8(16, 1) ROUND8(24, 1)
    STEP(32, 7, 0,     0) STEP(33, 6, 4096,  0)
    STEP(34, 5, 8192,  0) STEP(35, 4, 12288, 0)
    STEP(36, 3, 16384, 0) STEP(37, 2, 20480, 0)
    STEP(38, 1, 24576, 0) STEP(39, 0, 28672, 0)
#undef ROUND8
#undef STEP

    #pragma unroll
    for (int b = 0; b < 8; ++b) {
        acc[b].x += __shfl_xor(acc[b].x, 32);
        acc[b].y += __shfl_xor(acc[b].y, 32);
        acc[b].z += __shfl_xor(acc[b].z, 32);
        acc[b].w += __shfl_xor(acc[b].w, 32);
    }
    __syncthreads();   // phi reads done; smem reused for partials
    if (kh == 0) {
        int base = (w * 32 + h4) * 33;
        #pragma unroll
        for (int b = 0; b < 8; ++b) {
            smem[base + b * 4 + 0] = acc[b].x;
            smem[base + b * 4 + 1] = acc[b].y;
            smem[base + b * 4 + 2] = acc[b].z;
            smem[base + b * 4 + 3] = acc[b].w;
        }
    }
    __syncthreads();

    int h4r = t & 31, br = t >> 5;
    float s0 = 0.f, s1 = 0.f, s2 = 0.f, s3 = 0.f;
    #pragma unroll
    for (int wv = 0; wv < 4; ++wv) {
        int idx = (wv * 32 + h4r) * 33 + br * 4;
        s0 += smem[idx + 0]; s1 += smem[idx + 1];
        s2 += smem[idx + 2]; s3 += smem[idx + 3];
    }
    float* pb = part + (long)blockIdx.x * 1024;
    *reinterpret_cast<float4*>(&pb[br * H + h4r * 4]) =
        make_float4(s0, s1, s2, s3);
}

// ---------------- hidden[y*1024+j] = sum_x part[y,x,j] ----------------
__global__ __launch_bounds__(256) void k_reduce(const float* __restrict__ part,
                                                float* __restrict__ hidden) {
    int idx = blockIdx.x * 256 + threadIdx.x;      // [0, 2048)
    int c = blockIdx.y;                            // [0, 16)
    int y = idx >> 10, j = idx & 1023;
    const float* p = part + (long)y * XB * 1024 + j;
    int x0 = (XB * c) >> 4, x1 = (XB * (c + 1)) >> 4;
    float s0 = 0.f, s1 = 0.f, s2 = 0.f, s3 = 0.f;
    int x = x0;
    for (; x + 3 < x1; x += 4) {
        s0 += p[(long)(x + 0) * 1024];
        s1 += p[(long)(x + 1) * 1024];
        s2 += p[(long)(x + 2) * 1024];
        s3 += p[(long)(x + 3) * 1024];
    }
    for (; x < x1; ++x) s0 += p[(long)x * 1024];
    unsafeAtomicAdd(&hidden[y * 1024 + j], s0 + s1 + s2 + s3);
}

// ---------------- out[b, head*2+j] = elu(hidden+ba) @ wb + bb ----------------
__global__ __launch_bounds__(64) void k_final(const float* __restrict__ hidden,
                                              const float* __restrict__ b0a,
                                              const float* __restrict__ w0b,
                                              const float* __restrict__ b0b,
                                              const float* __restrict__ b1a,
                                              const float* __restrict__ w1b,
                                              const float* __restrict__ b1b,
                                              float* __restrict__ out) {
    int t = threadIdx.x;
    if (t >= 32) return;
    int head = t >> 4, b = (t >> 1) & 7, j = t & 1;
    const float* hid = hidden + head * (8 * H) + b * H;
    const float* ba = head ? b1a : b0a;
    const float* wb = head ? w1b : w0b;
    const float* bb = head ? b1b : b0b;
    float acc = 0.0f;
    for (int hh = 0; hh < H; ++hh)
        acc += elu_f(hid[hh] + ba[hh]) * wb[hh * 2 + j];
    out[b * 4 + head * 2 + j] = acc + bb[j];
}

extern "C" void kernel_launch(void* const* d_in, const int* in_sizes, int n_in,
                              void* d_out, int out_size, void* d_ws, size_t ws_size,
                              hipStream_t stream) {
    const float* x      = (const float*)d_in[0];
    const int*   edges  = (const int*)d_in[1];
    const float* emb    = (const float*)d_in[2];
    const float* c1_pw1 = (const float*)d_in[3];
    const float* c1_pw2 = (const float*)d_in[4];
    const float* c1_uw1 = (const float*)d_in[5];
    const float* c1_ub1 = (const float*)d_in[6];
    const float* c1_uw2 = (const float*)d_in[7];
    const float* c1_ub2 = (const float*)d_in[8];
    const float* c2_pw1 = (const float*)d_in[9];
    const float* c2_pw2 = (const float*)d_in[10];
    const float* c2_uw1 = (const float*)d_in[11];
    const float* c2_ub1 = (const float*)d_in[12];
    const float* c2_uw2 = (const float*)d_in[13];
    const float* c2_ub2 = (const float*)d_in[14];
    const float* w0a    = (const float*)d_in[15];
    const float* b0a    = (const float*)d_in[16];
    const float* w0b    = (const float*)d_in[17];
    const float* b0b    = (const float*)d_in[18];
    const float* w1a    = (const float*)d_in[19];
    const float* b1a    = (const float*)d_in[20];
    const float* w1b    = (const float*)d_in[21];
    const float* b1b    = (const float*)d_in[22];
    float* out = (float*)d_out;

    float* hA     = (float*)d_ws;          // [BN, D]
    float* hB     = hA + BND;
    float* Mu     = hB + BND;              // conv1 messages; aliased as `part`
    float* M2     = Mu + BND;              // conv2 messages
    float* hidden = M2 + BND;              // [2][8][H] = 2048 floats
    int* cnt      = (int*)(hidden + 2048); // [N]
    int* cursor   = cnt + N;               // [N]
    int* offs     = cursor + N;            // [N+1]
    int* elist    = offs + N + 1;          // [E]
    float* part   = Mu;                    // [2][XB][1024] = 2.048M floats <= BND

    hipMemsetAsync(hidden, 0, (2048 + 2 * N) * sizeof(float), stream);

    k_count<<<(E + 255) / 256, 256, 0, stream>>>(edges, cnt);
    k_scan<<<1, 256, 0, stream>>>(cnt, offs);
    k_fill<<<(E + 255) / 256, 256, 0, stream>>>(edges, offs, cursor, elist);

    // conv1 prepare (also materializes hA = x*emb)
    k_prepare<<<(BN + 127) / 128, 512, 0, stream>>>(x, emb, nullptr, c1_pw1, c1_pw2, Mu, hA);
    // conv1 gather+update, fused with conv2 prepare (writes hB and M2)
    k_conv<1><<<BN / 32, 512, 0, stream>>>(hA, Mu, offs, elist,
                                           c1_uw1, c1_ub1, c1_uw2, c1_ub2, hB,
                                           c2_pw1, c2_pw2, M2);
    // conv2 gather+update (writes hA = phi)
    k_conv<0><<<BN / 32, 512, 0, stream>>>(hB, M2, offs, elist,
                                           c2_uw1, c2_ub1, c2_uw2, c2_ub2, hA,
                                           nullptr, nullptr, nullptr);

    // heads: one dispatch per head
    k_head<<<XB, 256, 0, stream>>>(hA, w0a, part);
    k_head<<<XB, 256, 0, stream>>>(hA, w1a, part + (long)XB * 1024);
    k_reduce<<<dim3(8, 16), 256, 0, stream>>>(part, hidden);
    k_final<<<1, 64, 0, stream>>>(hidden, b0a, w0b, b0b, b1a, w1b, b1b, out);
}

// Round 8
// 626.658 us; speedup vs baseline: 1.1411x; 1.1411x over previous
//
#include <hip/hip_runtime.h>

// GNN TARnet: h = x*emb -> 2x graph conv -> two prob heads.
// R11: batch-contiguous gather. R10 proved the gather is request-throughput
//     bound (~3 TB/s wall; more waves made it WORSE: 101->149us, VALU 22->16%).
//     Change traffic shape, not parallelism: M stored node-major [N][8][64]
//     (2KB/node). One wave per node; each edge = two coalesced 1024B reads
//     covering all 8 batches; no shuffle reduction. 8x fewer index loads,
//     8x fewer random segments, same bytes. Grid 625, 64 rows/block (R9's
//     proven GEMM shape). k_head/k_reduce/k_final/CSR byte-identical.

constexpr int B = 8, N = 5000, E = 160000, D = 64, H = 128;
constexpr int BN = B * N;           // 40000
constexpr int ND = N * D;           // 320000
constexpr long BND = (long)BN * D;  // 2,560,000
constexpr int KC = 320;             // k-chunk per head block
constexpr int NIT = KC / 8;         // 40 k-iters per thread
constexpr int XB = ND / KC;         // 1000 x-blocks per head

using f32x4 = __attribute__((ext_vector_type(4))) float;

__device__ __forceinline__ float elu_f(float x) {
    return x > 0.0f ? x : __expf(x) - 1.0f;
}

__device__ __forceinline__ void g2lds16(const float* g, float* l) {
    __builtin_amdgcn_global_load_lds(
        (const __attribute__((address_space(1))) void*)g,
        (__attribute__((address_space(3))) void*)l, 16, 0, 0);
}

// ---------------- CSR build (edges grouped by child) ----------------
__global__ __launch_bounds__(256) void k_count(const int* __restrict__ edges,
                                               int* __restrict__ cnt) {
    int i = blockIdx.x * 256 + threadIdx.x;
    if (i < E) atomicAdd(&cnt[edges[2 * i + 1]], 1);
}

__global__ __launch_bounds__(256) void k_scan(const int* __restrict__ cnt,
                                              int* __restrict__ offs) {
    __shared__ int part[256];
    int t = threadIdx.x;
    const int CH = 20;
    int base = t * CH;
    int s = 0;
    for (int i = 0; i < CH; ++i) { int idx = base + i; if (idx < N) s += cnt[idx]; }
    part[t] = s;
    __syncthreads();
    for (int off = 1; off < 256; off <<= 1) {
        int add = (t >= off) ? part[t - off] : 0;
        __syncthreads();
        part[t] += add;
        __syncthreads();
    }
    int run = part[t] - s;
    for (int i = 0; i < CH; ++i) {
        int idx = base + i;
        if (idx < N) { offs[idx] = run; run += cnt[idx]; }
    }
    if (t == 255) offs[N] = run;
}

__global__ __launch_bounds__(256) void k_fill(const int* __restrict__ edges,
                                              const int* __restrict__ offs,
                                              int* __restrict__ cursor,
                                              int* __restrict__ elist) {
    int i = blockIdx.x * 256 + threadIdx.x;
    if (i < E) {
        int child = edges[2 * i + 1];
        int pos = offs[child] + atomicAdd(&cursor[child], 1);
        elist[pos] = edges[2 * i];
    }
}

// ---------------- prepare (conv1 only): M = elu(elu(h @ W1) @ W2) ----------
// R11: M written NODE-MAJOR: M[(n*8 + b)*64 + c].
__global__ __launch_bounds__(512) void k_prepare(const float* __restrict__ xsrc,
                                                 const float* __restrict__ emb,
                                                 const float* __restrict__ W1,
                                                 const float* __restrict__ W2,
                                                 float* __restrict__ M,
                                                 float* __restrict__ hwt) {
    __shared__ float sW1[64 * 64];      // 16 KB
    __shared__ float sP[128 * 65];      // 33.3 KB
    int t = threadIdx.x;
    int r0 = blockIdx.x * 128;
    for (int i = t; i < 4096; i += 512) sW1[i] = W1[i];
    for (int i = t; i < 128 * 64; i += 512) {
        int r = i >> 6, c = i & 63;
        int row = r0 + r;
        float v = 0.0f;
        if (row < BN) {
            int n = row % N;
            v = xsrc[row] * emb[n * 64 + c];
            hwt[(long)row * 64 + c] = v;
        }
        sP[r * 65 + c] = v;
    }
    __syncthreads();

    int cg = t & 15, rg = t >> 4;
    float acc[4][4] = {};
    #pragma unroll 4
    for (int k = 0; k < 64; ++k) {
        float a[4];
        #pragma unroll
        for (int i = 0; i < 4; ++i) a[i] = sP[(rg * 4 + i) * 65 + k];
        float4 bb = *reinterpret_cast<const float4*>(&sW1[k * 64 + cg * 4]);
        #pragma unroll
        for (int i = 0; i < 4; ++i) {
            acc[i][0] += a[i] * bb.x; acc[i][1] += a[i] * bb.y;
            acc[i][2] += a[i] * bb.z; acc[i][3] += a[i] * bb.w;
        }
    }
    __syncthreads();
    #pragma unroll
    for (int i = 0; i < 4; ++i)
        #pragma unroll
        for (int j = 0; j < 4; ++j)
            sP[(rg * 4 + i) * 65 + cg * 4 + j] = elu_f(acc[i][j]);
    __syncthreads();

    float acc2[4][4] = {};
    #pragma unroll 4
    for (int k = 0; k < 64; ++k) {
        float a[4];
        #pragma unroll
        for (int i = 0; i < 4; ++i) a[i] = sP[(rg * 4 + i) * 65 + k];
        float4 bb = *reinterpret_cast<const float4*>(&W2[k * 64 + cg * 4]);
        #pragma unroll
        for (int i = 0; i < 4; ++i) {
            acc2[i][0] += a[i] * bb.x; acc2[i][1] += a[i] * bb.y;
            acc2[i][2] += a[i] * bb.z; acc2[i][3] += a[i] * bb.w;
        }
    }
    #pragma unroll
    for (int i = 0; i < 4; ++i) {
        int row = r0 + rg * 4 + i;
        if (row < BN) {
            int b = row / N;
            int n = row - b * N;
            float4 o = make_float4(elu_f(acc2[i][0]), elu_f(acc2[i][1]),
                                   elu_f(acc2[i][2]), elu_f(acc2[i][3]));
            *reinterpret_cast<float4*>(&M[((long)n * 8 + b) * 64 + cg * 4]) = o;
        }
    }
}

// ---------------- fused conv: gather + update FFN (+ optional next-prepare) ----
// R11: M node-major [N][8][64]. Block = 8 nodes x 8 batches = 64 rows.
// Gather: wave wv owns node n0+wv; per edge two coalesced 1024B float4 reads
// (lane l owns (b=l>>4,c4=l&15) and (b=4+(l>>4),c4)). No shuffles.
// GEMMs: R9 shape, 2 rows/thread. LDS row lr = n_local*8 + b.
template <int PREP>
__global__ __launch_bounds__(512, 8) void k_conv(const float* __restrict__ h,
                                                 const float* __restrict__ M,
                                                 const int* __restrict__ offs,
                                                 const int* __restrict__ elist,
                                                 const float* __restrict__ W1u,  // [128][64]
                                                 const float* __restrict__ b1u,
                                                 const float* __restrict__ W2u,  // [64][64]
                                                 const float* __restrict__ b2u,
                                                 float* __restrict__ hout,
                                                 const float* __restrict__ W1p,  // [64][64]
                                                 const float* __restrict__ W2p,  // [64][64]
                                                 float* __restrict__ Mout) {
    __shared__ float sP[64 * 129];      // 33 KB; rows lr = n_local*8 + b
    int t = threadIdx.x;
    int n0 = blockIdx.x * 8;

    // A1: stage h rows -> sP cols [0,64): 1024 float4, 2 per thread
    #pragma unroll
    for (int q = 0; q < 2; ++q) {
        int s = t + q * 512;
        int lr = s >> 4, c4 = s & 15;
        int nl = lr >> 3, b = lr & 7;
        long grow = (long)b * N + (n0 + nl);
        float4 v = *reinterpret_cast<const float4*>(&h[grow * 64 + c4 * 4]);
        int base = lr * 129 + c4 * 4;
        sP[base + 0] = v.x; sP[base + 1] = v.y;
        sP[base + 2] = v.z; sP[base + 3] = v.w;
    }
    // A2: gather -> sP cols [64,128)
    {
        int wv = t >> 6, l = t & 63;
        int n = n0 + wv;
        int e0 = __builtin_amdgcn_readfirstlane(offs[n]);
        int e1 = __builtin_amdgcn_readfirstlane(offs[n + 1]);
        float4 a1 = make_float4(0.f, 0.f, 0.f, 0.f);
        float4 a2 = make_float4(0.f, 0.f, 0.f, 0.f);
        float4 a3 = make_float4(0.f, 0.f, 0.f, 0.f);
        float4 a4 = make_float4(0.f, 0.f, 0.f, 0.f);
        int e = e0;
        for (; e + 1 < e1; e += 2) {
            int p1 = elist[e], p2 = elist[e + 1];
            const float4* q1 = reinterpret_cast<const float4*>(M + (long)p1 * 512);
            const float4* q2 = reinterpret_cast<const float4*>(M + (long)p2 * 512);
            float4 v1 = q1[l], v2 = q1[64 + l];
            float4 v3 = q2[l], v4 = q2[64 + l];
            a1.x += v1.x; a1.y += v1.y; a1.z += v1.z; a1.w += v1.w;
            a2.x += v2.x; a2.y += v2.y; a2.z += v2.z; a2.w += v2.w;
            a3.x += v3.x; a3.y += v3.y; a3.z += v3.z; a3.w += v3.w;
            a4.x += v4.x; a4.y += v4.y; a4.z += v4.z; a4.w += v4.w;
        }
        if (e < e1) {
            int p = elist[e];
            const float4* q = reinterpret_cast<const float4*>(M + (long)p * 512);
            float4 v1 = q[l], v2 = q[64 + l];
            a1.x += v1.x; a1.y += v1.y; a1.z += v1.z; a1.w += v1.w;
            a2.x += v2.x; a2.y += v2.y; a2.z += v2.z; a2.w += v2.w;
        }
        a1.x += a3.x; a1.y += a3.y; a1.z += a3.z; a1.w += a3.w;
        a2.x += a4.x; a2.y += a4.y; a2.z += a4.z; a2.w += a4.w;
        int c4 = l & 15, br = l >> 4;
        int base1 = (wv * 8 + br) * 129 + 64 + c4 * 4;
        int base2 = (wv * 8 + 4 + br) * 129 + 64 + c4 * 4;
        sP[base1 + 0] = a1.x; sP[base1 + 1] = a1.y;
        sP[base1 + 2] = a1.z; sP[base1 + 3] = a1.w;
        sP[base2 + 0] = a2.x; sP[base2 + 1] = a2.y;
        sP[base2 + 2] = a2.z; sP[base2 + 3] = a2.w;
    }
    __syncthreads();

    int cg = t & 15, rg = t >> 4;    // rows 2rg, 2rg+1
    // B: update GEMM1 over k=0..128 (W1u broadcast from global/L1)
    float acc[2][4] = {};
    #pragma unroll 4
    for (int k = 0; k < 128; ++k) {
        float a0 = sP[(rg * 2 + 0) * 129 + k];
        float a1 = sP[(rg * 2 + 1) * 129 + k];
        float4 bb = *reinterpret_cast<const float4*>(&W1u[k * 64 + cg * 4]);
        acc[0][0] += a0 * bb.x; acc[0][1] += a0 * bb.y; acc[0][2] += a0 * bb.z; acc[0][3] += a0 * bb.w;
        acc[1][0] += a1 * bb.x; acc[1][1] += a1 * bb.y; acc[1][2] += a1 * bb.z; acc[1][3] += a1 * bb.w;
    }
    float4 bv1 = *reinterpret_cast<const float4*>(&b1u[cg * 4]);
    __syncthreads();
    #pragma unroll
    for (int i = 0; i < 2; ++i) {
        int base = (rg * 2 + i) * 129 + cg * 4;
        sP[base + 0] = elu_f(acc[i][0] + bv1.x);
        sP[base + 1] = elu_f(acc[i][1] + bv1.y);
        sP[base + 2] = elu_f(acc[i][2] + bv1.z);
        sP[base + 3] = elu_f(acc[i][3] + bv1.w);
    }
    __syncthreads();

    // C: update GEMM2 over k=0..64
    float acc2[2][4] = {};
    #pragma unroll 4
    for (int k = 0; k < 64; ++k) {
        float a0 = sP[(rg * 2 + 0) * 129 + k];
        float a1 = sP[(rg * 2 + 1) * 129 + k];
        float4 bb = *reinterpret_cast<const float4*>(&W2u[k * 64 + cg * 4]);
        acc2[0][0] += a0 * bb.x; acc2[0][1] += a0 * bb.y; acc2[0][2] += a0 * bb.z; acc2[0][3] += a0 * bb.w;
        acc2[1][0] += a1 * bb.x; acc2[1][1] += a1 * bb.y; acc2[1][2] += a1 * bb.z; acc2[1][3] += a1 * bb.w;
    }
    float4 bv2 = *reinterpret_cast<const float4*>(&b2u[cg * 4]);
    #pragma unroll
    for (int i = 0; i < 2; ++i) {
        int lr = rg * 2 + i;
        int nl = lr >> 3, b = lr & 7;
        float4 o = make_float4(acc2[i][0] + bv2.x, acc2[i][1] + bv2.y,
                               acc2[i][2] + bv2.z, acc2[i][3] + bv2.w);
        *reinterpret_cast<float4*>(
            &hout[((long)b * N + (n0 + nl)) * 64 + cg * 4]) = o;
        if (PREP) {  // stash into sP cols [64,128) (disjoint from GEMM2 reads)
            int base = lr * 129 + 64 + cg * 4;
            sP[base + 0] = o.x; sP[base + 1] = o.y;
            sP[base + 2] = o.z; sP[base + 3] = o.w;
        }
    }

    if (PREP) {
        __syncthreads();
        // D1: p1 = elu(rows @ W1p), reads sP cols [64,128), writes cols [0,64)
        float acc3[2][4] = {};
        #pragma unroll 4
        for (int k = 0; k < 64; ++k) {
            float a0 = sP[(rg * 2 + 0) * 129 + 64 + k];
            float a1 = sP[(rg * 2 + 1) * 129 + 64 + k];
            float4 bb = *reinterpret_cast<const float4*>(&W1p[k * 64 + cg * 4]);
            acc3[0][0] += a0 * bb.x; acc3[0][1] += a0 * bb.y; acc3[0][2] += a0 * bb.z; acc3[0][3] += a0 * bb.w;
            acc3[1][0] += a1 * bb.x; acc3[1][1] += a1 * bb.y; acc3[1][2] += a1 * bb.z; acc3[1][3] += a1 * bb.w;
        }
        #pragma unroll
        for (int i = 0; i < 2; ++i) {
            int base = (rg * 2 + i) * 129 + cg * 4;
            sP[base + 0] = elu_f(acc3[i][0]);
            sP[base + 1] = elu_f(acc3[i][1]);
            sP[base + 2] = elu_f(acc3[i][2]);
            sP[base + 3] = elu_f(acc3[i][3]);
        }
        __syncthreads();
        // D2: Mout = elu(p1 @ W2p), node-major
        float acc4[2][4] = {};
        #pragma unroll 4
        for (int k = 0; k < 64; ++k) {
            float a0 = sP[(rg * 2 + 0) * 129 + k];
            float a1 = sP[(rg * 2 + 1) * 129 + k];
            float4 bb = *reinterpret_cast<const float4*>(&W2p[k * 64 + cg * 4]);
            acc4[0][0] += a0 * bb.x; acc4[0][1] += a0 * bb.y; acc4[0][2] += a0 * bb.z; acc4[0][3] += a0 * bb.w;
            acc4[1][0] += a1 * bb.x; acc4[1][1] += a1 * bb.y; acc4[1][2] += a1 * bb.z; acc4[1][3] += a1 * bb.w;
        }
        #pragma unroll
        for (int i = 0; i < 2; ++i) {
            int lr = rg * 2 + i;
            int nl = lr >> 3, b = lr & 7;
            float4 o = make_float4(elu_f(acc4[i][0]), elu_f(acc4[i][1]),
                                   elu_f(acc4[i][2]), elu_f(acc4[i][3]));
            *reinterpret_cast<float4*>(
                &Mout[((long)(n0 + nl) * 8 + b) * 64 + cg * 4]) = o;
        }
    }
}

// ---------------- partial[xb,:] = per-block head GEMV partial (ONE head) ------
// One head per dispatch; hot loop identical to R6/R8.
__global__ __launch_bounds__(256) void k_head(const float* __restrict__ phi,   // [8][ND]
                                              const float* __restrict__ wa,    // [ND][H]
                                              float* __restrict__ part) {      // [XB][1024]
    __shared__ float smem[4 * 32 * 33];              // 16.9 KB; phi chunk + partials
    __shared__ __align__(16) float wb[8][1024];      // 32 KB ring (8 x 4KB)
    int t = threadIdx.x;
    int k0 = blockIdx.x * KC;

    #pragma unroll
    for (int b = 0; b < 8; ++b)
        for (int kk = t; kk < KC; kk += 256)
            smem[b * KC + kk] = phi[(long)b * ND + k0 + kk];
    __syncthreads();

    int w = t >> 6, l = t & 63;
    int h4 = l & 31, kh = l >> 5;
    int kl = w * 2 + kh;                       // [0,8)
    const float* wp = wa + (long)(k0 + kl) * H + h4 * 4;

    float4 acc[8];
    #pragma unroll
    for (int b = 0; b < 8; ++b) acc[b] = make_float4(0.f, 0.f, 0.f, 0.f);

    unsigned my_off =
        (unsigned)(size_t)(__attribute__((address_space(3))) float*)&wb[0][0]
        + (unsigned)t * 16u;

    const float* wq = wp;
    #pragma unroll
    for (int j = 0; j < 8; ++j) {
        g2lds16(wq, &wb[j][w * 256]);
        wq += 8 * H;
    }

#define STEP(I, CNT, OFF, RE)                                              \
    {                                                                      \
        asm volatile("s_waitcnt vmcnt(" #CNT ")" ::: "memory");            \
        __builtin_amdgcn_sched_barrier(0);                                 \
        f32x4 w4;                                                          \
        asm volatile("ds_read_b128 %0, %1 offset:" #OFF                    \
                     : "=v"(w4) : "v"(my_off));                            \
        float pv[8];                                                       \
        _Pragma("unroll")                                                  \
        for (int b = 0; b < 8; ++b)                                        \
            pv[b] = smem[b * KC + (I) * 8 + kl];                           \
        asm volatile("s_waitcnt lgkmcnt(0)" ::: "memory");                 \
        __builtin_amdgcn_sched_barrier(0);                                 \
        _Pragma("unroll")                                                  \
        for (int b = 0; b < 8; ++b) {                                      \
            acc[b].x += pv[b] * w4.x; acc[b].y += pv[b] * w4.y;            \
            acc[b].z += pv[b] * w4.z; acc[b].w += pv[b] * w4.w;            \
        }                                                                  \
        if (RE) {                                                          \
            g2lds16(wq, &wb[(I) & 7][w * 256]);                            \
            wq += 8 * H;                                                   \
        }                                                                  \
    }

#define ROUND8(BASE, RE)                                                   \
    STEP(BASE + 0, 7, 0,     RE) STEP(BASE + 1, 7, 4096,  RE)              \
    STEP(BASE + 2, 7, 8192,  RE) STEP(BASE + 3, 7, 12288, RE)              \
    STEP(BASE + 4, 7, 16384, RE) STEP(BASE + 5, 7, 20480, RE)              \
    STEP(BASE + 6, 7, 24576, RE) STEP(BASE + 7, 7, 28672, RE)

    ROUND8(0, 1) ROUND8(8, 1) ROUND8(16, 1) ROUND8(24, 1)
    STEP(32, 7, 0,     0) STEP(33, 6, 4096,  0)
    STEP(34, 5, 8192,  0) STEP(35, 4, 12288, 0)
    STEP(36, 3, 16384, 0) STEP(37, 2, 20480, 0)
    STEP(38, 1, 24576, 0) STEP(39, 0, 28672, 0)
#undef ROUND8
#undef STEP

    #pragma unroll
    for (int b = 0; b < 8; ++b) {
        acc[b].x += __shfl_xor(acc[b].x, 32);
        acc[b].y += __shfl_xor(acc[b].y, 32);
        acc[b].z += __shfl_xor(acc[b].z, 32);
        acc[b].w += __shfl_xor(acc[b].w, 32);
    }
    __syncthreads();   // phi reads done; smem reused for partials
    if (kh == 0) {
        int base = (w * 32 + h4) * 33;
        #pragma unroll
        for (int b = 0; b < 8; ++b) {
            smem[base + b * 4 + 0] = acc[b].x;
            smem[base + b * 4 + 1] = acc[b].y;
            smem[base + b * 4 + 2] = acc[b].z;
            smem[base + b * 4 + 3] = acc[b].w;
        }
    }
    __syncthreads();

    int h4r = t & 31, br = t >> 5;
    float s0 = 0.f, s1 = 0.f, s2 = 0.f, s3 = 0.f;
    #pragma unroll
    for (int wv = 0; wv < 4; ++wv) {
        int idx = (wv * 32 + h4r) * 33 + br * 4;
        s0 += smem[idx + 0]; s1 += smem[idx + 1];
        s2 += smem[idx + 2]; s3 += smem[idx + 3];
    }
    float* pb = part + (long)blockIdx.x * 1024;
    *reinterpret_cast<float4*>(&pb[br * H + h4r * 4]) =
        make_float4(s0, s1, s2, s3);
}

// ---------------- hidden[y*1024+j] = sum_x part[y,x,j] ----------------
__global__ __launch_bounds__(256) void k_reduce(const float* __restrict__ part,
                                                float* __restrict__ hidden) {
    int idx = blockIdx.x * 256 + threadIdx.x;      // [0, 2048)
    int c = blockIdx.y;                            // [0, 16)
    int y = idx >> 10, j = idx & 1023;
    const float* p = part + (long)y * XB * 1024 + j;
    int x0 = (XB * c) >> 4, x1 = (XB * (c + 1)) >> 4;
    float s0 = 0.f, s1 = 0.f, s2 = 0.f, s3 = 0.f;
    int x = x0;
    for (; x + 3 < x1; x += 4) {
        s0 += p[(long)(x + 0) * 1024];
        s1 += p[(long)(x + 1) * 1024];
        s2 += p[(long)(x + 2) * 1024];
        s3 += p[(long)(x + 3) * 1024];
    }
    for (; x < x1; ++x) s0 += p[(long)x * 1024];
    unsafeAtomicAdd(&hidden[y * 1024 + j], s0 + s1 + s2 + s3);
}

// ---------------- out[b, head*2+j] = elu(hidden+ba) @ wb + bb ----------------
__global__ __launch_bounds__(64) void k_final(const float* __restrict__ hidden,
                                              const float* __restrict__ b0a,
                                              const float* __restrict__ w0b,
                                              const float* __restrict__ b0b,
                                              const float* __restrict__ b1a,
                                              const float* __restrict__ w1b,
                                              const float* __restrict__ b1b,
                                              float* __restrict__ out) {
    int t = threadIdx.x;
    if (t >= 32) return;
    int head = t >> 4, b = (t >> 1) & 7, j = t & 1;
    const float* hid = hidden + head * (8 * H) + b * H;
    const float* ba = head ? b1a : b0a;
    const float* wb = head ? w1b : w0b;
    const float* bb = head ? b1b : b0b;
    float acc = 0.0f;
    for (int hh = 0; hh < H; ++hh)
        acc += elu_f(hid[hh] + ba[hh]) * wb[hh * 2 + j];
    out[b * 4 + head * 2 + j] = acc + bb[j];
}

extern "C" void kernel_launch(void* const* d_in, const int* in_sizes, int n_in,
                              void* d_out, int out_size, void* d_ws, size_t ws_size,
                              hipStream_t stream) {
    const float* x      = (const float*)d_in[0];
    const int*   edges  = (const int*)d_in[1];
    const float* emb    = (const float*)d_in[2];
    const float* c1_pw1 = (const float*)d_in[3];
    const float* c1_pw2 = (const float*)d_in[4];
    const float* c1_uw1 = (const float*)d_in[5];
    const float* c1_ub1 = (const float*)d_in[6];
    const float* c1_uw2 = (const float*)d_in[7];
    const float* c1_ub2 = (const float*)d_in[8];
    const float* c2_pw1 = (const float*)d_in[9];
    const float* c2_pw2 = (const float*)d_in[10];
    const float* c2_uw1 = (const float*)d_in[11];
    const float* c2_ub1 = (const float*)d_in[12];
    const float* c2_uw2 = (const float*)d_in[13];
    const float* c2_ub2 = (const float*)d_in[14];
    const float* w0a    = (const float*)d_in[15];
    const float* b0a    = (const float*)d_in[16];
    const float* w0b    = (const float*)d_in[17];
    const float* b0b    = (const float*)d_in[18];
    const float* w1a    = (const float*)d_in[19];
    const float* b1a    = (const float*)d_in[20];
    const float* w1b    = (const float*)d_in[21];
    const float* b1b    = (const float*)d_in[22];
    float* out = (float*)d_out;

    float* hA     = (float*)d_ws;          // [BN, D] b-major
    float* hB     = hA + BND;              // [BN, D] b-major
    float* Mu     = hB + BND;              // conv1 messages [N][8][64]; aliased part
    float* M2     = Mu + BND;              // conv2 messages [N][8][64]
    float* hidden = M2 + BND;              // [2][8][H] = 2048 floats
    int* cnt      = (int*)(hidden + 2048); // [N]
    int* cursor   = cnt + N;               // [N]
    int* offs     = cursor + N;            // [N+1]
    int* elist    = offs + N + 1;          // [E]
    float* part   = Mu;                    // [2][XB][1024] = 2.048M floats <= BND

    hipMemsetAsync(hidden, 0, (2048 + 2 * N) * sizeof(float), stream);

    k_count<<<(E + 255) / 256, 256, 0, stream>>>(edges, cnt);
    k_scan<<<1, 256, 0, stream>>>(cnt, offs);
    k_fill<<<(E + 255) / 256, 256, 0, stream>>>(edges, offs, cursor, elist);

    // conv1 prepare (also materializes hA = x*emb); Mu node-major
    k_prepare<<<(BN + 127) / 128, 512, 0, stream>>>(x, emb, c1_pw1, c1_pw2, Mu, hA);
    // conv1 gather+update, fused with conv2 prepare (writes hB and M2)
    k_conv<1><<<N / 8, 512, 0, stream>>>(hA, Mu, offs, elist,
                                         c1_uw1, c1_ub1, c1_uw2, c1_ub2, hB,
                                         c2_pw1, c2_pw2, M2);
    // conv2 gather+update (writes hA = phi)
    k_conv<0><<<N / 8, 512, 0, stream>>>(hB, M2, offs, elist,
                                         c2_uw1, c2_ub1, c2_uw2, c2_ub2, hA,
                                         nullptr, nullptr, nullptr);

    // heads: one dispatch per head
    k_head<<<XB, 256, 0, stream>>>(hA, w0a, part);
    k_head<<<XB, 256, 0, stream>>>(hA, w1a, part + (long)XB * 1024);
    k_reduce<<<dim3(8, 16), 256, 0, stream>>>(part, hidden);
    k_final<<<1, 64, 0, stream>>>(hidden, b0a, w0b, b0b, b1a, w1b, b1b, out);
}